// Round 8
// baseline (524.175 us; speedup 1.0000x reference)
//
#include <hip/hip_runtime.h>
#include <hip/hip_bf16.h>
#include <stdint.h>

#define N_ROWS 200000
#define C_DIM  128
#define TAPS   27
#define EPS    1e-5f

typedef __attribute__((ext_vector_type(8)))  short  short8;
typedef __attribute__((ext_vector_type(16))) float  floatx16;

#define SBAR()  __builtin_amdgcn_s_barrier()
#define SCHED() __builtin_amdgcn_sched_barrier(0)
#define WAITV(n) __builtin_amdgcn_s_waitcnt(0xF70 | (n))   // vmcnt(n), n<=15
#define LGKM0() asm volatile("s_waitcnt lgkmcnt(0)" ::: "memory")

__device__ __forceinline__ unsigned int f2bf(float f) {
  union { float f; unsigned int u; } v; v.f = f;
  unsigned int r = v.u + 0x7FFFu + ((v.u >> 16) & 1u);   // RNE, inputs finite
  return r >> 16;
}

__device__ __forceinline__ void glds16(const unsigned short* g, unsigned short* l) {
  __builtin_amdgcn_global_load_lds(
      (const __attribute__((address_space(1))) unsigned int*)g,
      (__attribute__((address_space(3))) unsigned int*)l, 16, 0, 0);
}

// ---------------- feats fp32 -> bf16 ----------------
__global__ __launch_bounds__(256) void k_cast(const float* __restrict__ in,
                                              unsigned short* __restrict__ out, int n8) {
  int i = blockIdx.x * 256 + threadIdx.x;
  if (i >= n8) return;
  const float4* p = (const float4*)in + (size_t)i * 2;
  float4 a = p[0], b = p[1];
  uint4 v;
  v.x = f2bf(a.x) | (f2bf(a.y) << 16);
  v.y = f2bf(a.z) | (f2bf(a.w) << 16);
  v.z = f2bf(b.x) | (f2bf(b.y) << 16);
  v.w = f2bf(b.z) | (f2bf(b.w) << 16);
  *(uint4*)(out + (size_t)i * 8) = v;
}

// ---------------- nidx [N][27] -> nidxT [27][N] ----------------
__global__ __launch_bounds__(256) void k_tr(const int* __restrict__ in,
                                            int* __restrict__ outT) {
  __shared__ int t[1728];
  const int tile = blockIdx.x;                 // 3125 tiles x 64 rows (exact)
  const int* src = in + (size_t)tile * 1728;
  for (int e = threadIdx.x; e < 1728; e += 256) t[e] = src[e];
  __syncthreads();
  const int base = tile * 64;
  for (int o = threadIdx.x; o < 1728; o += 256) {
    int k = o >> 6, r = o & 63;
    outT[(size_t)k * N_ROWS + base + r] = t[r * 27 + k];
  }
}

// ---- fold Linear into conv weights; emit MFMA B-fragment layout ----
// wfrag[k][qr(4)][nt(4)][sh(2)][lane(64)][j(8)] (bf16): each K=32 quarter of a
// tap (4096 shorts = 8 KB) contiguous for ring staging. (unchanged from r7)
__global__ __launch_bounds__(256) void k_fold(const float* __restrict__ conv_w,
                                              const float* __restrict__ lin_w,
                                              const float* __restrict__ conv_b,
                                              const float* __restrict__ lin_b,
                                              unsigned short* __restrict__ wfrag,
                                              float* __restrict__ biasf) {
  __shared__ float lwT[128 * 128];  // 64 KB
  for (int e = threadIdx.x; e < 16384; e += 256) {
    int co = e >> 7, t = e & 127;
    lwT[t * 128 + (co ^ (t & 31))] = lin_w[e];
  }
  __syncthreads();

  int id = blockIdx.x * 256 + threadIdx.x;
  const int NW = TAPS * 4 * 4 * 2 * 64;  // 55296
  if (id < NW) {
    int l  = id & 63;
    int sh = (id >> 6) & 1;
    int nt = (id >> 7) & 3;
    int qr = (id >> 9) & 3;
    int k  = id >> 11;
    int s  = qr * 2 + sh;
    int ci0 = s * 16 + (l >> 5) * 8;
    int co  = nt * 32 + (l & 31);
    const float* cw = conv_w + ((size_t)(k * 128 + ci0)) * 128;
    float acc[8] = {0, 0, 0, 0, 0, 0, 0, 0};
    for (int t = 0; t < 128; ++t) {
      float lv = lwT[t * 128 + (co ^ (t & 31))];
#pragma unroll
      for (int j = 0; j < 8; ++j) acc[j] += cw[j * 128 + t] * lv;
    }
    uint4 v;
    v.x = f2bf(acc[0]) | (f2bf(acc[1]) << 16);
    v.y = f2bf(acc[2]) | (f2bf(acc[3]) << 16);
    v.z = f2bf(acc[4]) | (f2bf(acc[5]) << 16);
    v.w = f2bf(acc[6]) | (f2bf(acc[7]) << 16);
    *(uint4*)(wfrag + (size_t)id * 8) = v;
  } else if (id < NW + 128) {
    int co = id - NW;
    float s = lin_b[co];
    for (int t = 0; t < 128; ++t) s += conv_b[t] * lwT[t * 128 + (co ^ (t & 31))];
    biasf[co] = s;
  }
}

// ---------------- fused gather-GEMM + LayerNorm ----------------
// r8: FULL-LINE cooperative A-gather. 128 thr = 2 waves, 64 rows/block,
// LDS 32 KB (A 2x8KB wave-private + B 2-slot quarter ring 2x8KB) -> 5 blk/CU.
//   * A staged via global_load_lds with PER-LANE global source (m173): one
//     instr = 4 complete 256B rows (16 lanes/row contiguous) -> 8 full 128B
//     line requests, vs old 32 scattered 32B sub-line requests. 4x fewer
//     gather transactions, same bytes.
//   * LDS dest linear (row-major A tile IS lane-linear); chunk XOR-swizzle
//     (c ^ (r&7)) applied on the GLOBAL source side (rule #21) so fragment
//     ds_read_b128 is conflict-free (banks = 4*((2j+lh)^rx) tile all 32).
//   * A read once per tap into a0..a7 (32 VGPR) at p0; region restaged for
//     t+1 at p2 (wave-private: lgkm-ordered, no barriers, 2-step vmcnt lead).
//   * B: 2-slot quarter ring, 2 barriers/step (valid + consumed), stage into
//     the just-read slot after SBAR-b. Counted vmcnt ledger, never drained:
//     issues/step p0..p3 = [5,4,12,4] -> waits = [4,5,4,12]. rule #18 fences.
//   * MFMA order identical to r7 -> bitwise-identical output.
__global__ __launch_bounds__(128, 2) void k_main(const unsigned short* __restrict__ featsB,
                                                 const int* __restrict__ ntab,
                                                 const int nrs, const int nts,
                                                 const unsigned short* __restrict__ wfrag,
                                                 const float* __restrict__ biasf,
                                                 const float* __restrict__ lnw,
                                                 const float* __restrict__ lnb,
                                                 float* __restrict__ out) {
  __shared__ unsigned short A_lds[2][4096];  // 2 waves x 8 KB (32 rows x 256 B)
  __shared__ unsigned short B_lds[2][4096];  // 2 slots x 8 KB (K=32 quarter)

  const int tid = threadIdx.x;
  const int l   = tid & 63;
  const int w   = tid >> 6;          // 0..1
  const int l31 = l & 31;
  const int lh  = l >> 5;
  const int row0w = blockIdx.x * 64 + w * 32;
  const int gr  = row0w + l31;
  const int grc = (gr < N_ROWS) ? gr : 0;
  const int* np = ntab + (size_t)grc * nrs;

  // per-lane constants for A staging / reading
  const int q4 = l >> 4;                       // 0..3 (row within 4-row group)
  const int cb = (l & 15) ^ q4;                // swizzled chunk base (staging)
  const int rx = l31 & 7;                      // row swizzle key (reading)
  unsigned short* Aw = &A_lds[w][0];
  const unsigned short* Ar = Aw + l31 * 128;   // own row base (shorts)

// stage tap rows: 8 glds, instr i covers rows 4i..4i+3 (full 256B each)
#define ASTAGE(nv) do {                                                      \
    _Pragma("unroll")                                                        \
    for (int i_ = 0; i_ < 8; ++i_) {                                         \
      int nidl = __builtin_amdgcn_ds_bpermute((i_ << 4) + (q4 << 2), (nv));  \
      int cc = cb ^ ((i_ & 1) << 2);                                         \
      const unsigned short* s_ =                                             \
          featsB + ((size_t)(unsigned)nidl << 7) + (cc << 3);                \
      glds16(s_, Aw + i_ * 512);                                             \
    }                                                                        \
  } while (0)

// read own row's 8 fragments (swizzled, conflict-free)
#define AREAD() do {                                                         \
    a0 = *(const short8*)(Ar + (((0  + lh) ^ rx) << 3));                     \
    a1 = *(const short8*)(Ar + (((2  + lh) ^ rx) << 3));                     \
    a2 = *(const short8*)(Ar + (((4  + lh) ^ rx) << 3));                     \
    a3 = *(const short8*)(Ar + (((6  + lh) ^ rx) << 3));                     \
    a4 = *(const short8*)(Ar + (((8  + lh) ^ rx) << 3));                     \
    a5 = *(const short8*)(Ar + (((10 + lh) ^ rx) << 3));                     \
    a6 = *(const short8*)(Ar + (((12 + lh) ^ rx) << 3));                     \
    a7 = *(const short8*)(Ar + (((14 + lh) ^ rx) << 3));                     \
  } while (0)

// stage B quarter Qi into ring slot (4 glds/thread; wave w owns chunks 4w..)
#define BSTAGE(Qi, slot) do {                                                \
    int Qc = (Qi) > 4 * TAPS - 1 ? 4 * TAPS - 1 : (Qi);                      \
    const unsigned short* s_ = wfrag + (size_t)Qc * 4096 + w * 2048 + l * 8; \
    unsigned short* d_ = &B_lds[slot][w * 2048];                             \
    glds16(s_, d_);                                                          \
    glds16(s_ + 512, d_ + 512);                                              \
    glds16(s_ + 1024, d_ + 1024);                                            \
    glds16(s_ + 1536, d_ + 1536);                                            \
  } while (0)

// read 8 B chunks of the slot into regs
#define BREAD8(slot) do {                                                    \
    const unsigned short* bb = &B_lds[slot][l * 8];                          \
    b0 = *(const short8*)(bb + 0 * 512);                                     \
    b1 = *(const short8*)(bb + 1 * 512);                                     \
    b2 = *(const short8*)(bb + 2 * 512);                                     \
    b3 = *(const short8*)(bb + 3 * 512);                                     \
    b4 = *(const short8*)(bb + 4 * 512);                                     \
    b5 = *(const short8*)(bb + 5 * 512);                                     \
    b6 = *(const short8*)(bb + 6 * 512);                                     \
    b7 = *(const short8*)(bb + 7 * 512);                                     \
  } while (0)

// 8 MFMAs of one K=32 quarter: acc_nt <- chunks (2nt, 2nt+1); r7 order
#define MFMA8(aA, aB) do {                                                   \
    acc0 = __builtin_amdgcn_mfma_f32_32x32x16_bf16(aA, b0, acc0, 0, 0, 0);   \
    acc1 = __builtin_amdgcn_mfma_f32_32x32x16_bf16(aA, b2, acc1, 0, 0, 0);   \
    acc2 = __builtin_amdgcn_mfma_f32_32x32x16_bf16(aA, b4, acc2, 0, 0, 0);   \
    acc3 = __builtin_amdgcn_mfma_f32_32x32x16_bf16(aA, b6, acc3, 0, 0, 0);   \
    acc0 = __builtin_amdgcn_mfma_f32_32x32x16_bf16(aB, b1, acc0, 0, 0, 0);   \
    acc1 = __builtin_amdgcn_mfma_f32_32x32x16_bf16(aB, b3, acc1, 0, 0, 0);   \
    acc2 = __builtin_amdgcn_mfma_f32_32x32x16_bf16(aB, b5, acc2, 0, 0, 0);   \
    acc3 = __builtin_amdgcn_mfma_f32_32x32x16_bf16(aB, b7, acc3, 0, 0, 0);   \
  } while (0)

  floatx16 acc0 = {0.f}, acc1 = {0.f}, acc2 = {0.f}, acc3 = {0.f};
  short8 a0, a1, a2, a3, a4, a5, a6, a7;
  short8 b0, b1, b2, b3, b4, b5, b6, b7;

  // ---- prologue: nid(0),nid(1); drain; stage A(0), B(Q0->s0), B(Q1->s1) ----
  int nid0 = np[0];
  int n_stage = np[nts];             // nid(1): staged at (0,p2)
  int n_next;
  WAITV(0);                          // nid0, n_stage in regs
  SCHED();
  ASTAGE(nid0);                      // 8 glds (A(0))
  BSTAGE(0, 0);                      // 4
  BSTAGE(1, 1);                      // 4   -> outstanding: 16
  SCHED();

  for (int t = 0; t < TAPS; ++t) {
    // ---- p0: B slot0 = Q(4t); A(t) ready ----
    WAITV(4);                        // retire A(t)+B(4t); keep B(4t+1)'s 4
    AREAD();                         // 8 ds_read (wave-private, gated by wait)
    SCHED(); SBAR(); SCHED();        // slot0 valid for both waves
    BREAD8(0);
    LGKM0(); SCHED(); SBAR(); SCHED();  // all reads of slot0 done
    {
      const int tf = (t + 2 < TAPS) ? (t + 2) : (TAPS - 1);
      n_next = np[(size_t)tf * nts]; // 1 VMEM
    }
    BSTAGE(4 * t + 2, 0);            // 4 -> p0 issues 5
    SCHED();
    MFMA8(a0, a1);

    // ---- p1: slot1 = Q(4t+1) ----
    WAITV(5);                        // retire B(4t+1); keep p0's 5
    SCHED(); SBAR(); SCHED();
    BREAD8(1);
    LGKM0(); SCHED(); SBAR(); SCHED();
    BSTAGE(4 * t + 3, 1);            // 4
    SCHED();
    MFMA8(a2, a3);

    // ---- p2: slot0 = Q(4t+2); stage A(t+1) ----
    WAITV(4);                        // retire p0's 5 (B(4t+2)+nid); keep p1's 4
    SCHED(); SBAR(); SCHED();
    BREAD8(0);
    LGKM0(); SCHED(); SBAR(); SCHED();
    ASTAGE(n_stage);                 // 8 glds (A(t+1); A reads done at p0)
    BSTAGE(4 * t + 4, 0);            // 4 -> p2 issues 12
    SCHED();
    MFMA8(a4, a5);

    // ---- p3: slot1 = Q(4t+3) ----
    WAITV(12);                       // retire p1's 4 (B(4t+3)); keep p2's 12
    SCHED(); SBAR(); SCHED();
    BREAD8(1);
    LGKM0(); SCHED(); SBAR(); SCHED();
    BSTAGE(4 * t + 5, 1);            // 4
    SCHED();
    MFMA8(a6, a7);

    n_stage = n_next;
  }
  // leftover in-flight tail prefetches retire naturally; no drain.

  // ---- epilogue: bias + in-wave LayerNorm + store ----
  float e0 = biasf[l31], e1 = biasf[32 + l31], e2 = biasf[64 + l31], e3 = biasf[96 + l31];
  float g0 = lnw[l31],   g1 = lnw[32 + l31],   g2 = lnw[64 + l31],   g3 = lnw[96 + l31];
  float c0 = lnb[l31],   c1 = lnb[32 + l31],   c2 = lnb[64 + l31],   c3 = lnb[96 + l31];

#pragma unroll
  for (int r = 0; r < 16; ++r) {
    float x0 = acc0[r] + e0, x1 = acc1[r] + e1, x2 = acc2[r] + e2, x3 = acc3[r] + e3;
    float s = x0 + x1 + x2 + x3;
    float q = x0 * x0 + x1 * x1 + x2 * x2 + x3 * x3;
#pragma unroll
    for (int off = 16; off >= 1; off >>= 1) {
      s += __shfl_xor(s, off, 64);
      q += __shfl_xor(q, off, 64);
    }
    float mu  = s * (1.0f / 128.0f);
    float var = q * (1.0f / 128.0f) - mu * mu;
    float rs  = rsqrtf(var + EPS);
    int row   = (r & 3) + 8 * (r >> 2) + 4 * lh;  // 32x32 C/D row map
    int grow  = row0w + row;
    if (grow < N_ROWS) {
      float* o = out + (size_t)grow * 128;
      o[l31]      = (x0 - mu) * rs * g0 + c0;
      o[32 + l31] = (x1 - mu) * rs * g1 + c1;
      o[64 + l31] = (x2 - mu) * rs * g2 + c2;
      o[96 + l31] = (x3 - mu) * rs * g3 + c3;
    }
  }
}

extern "C" void kernel_launch(void* const* d_in, const int* in_sizes, int n_in,
                              void* d_out, int out_size, void* d_ws, size_t ws_size,
                              hipStream_t stream) {
  const float* feats  = (const float*)d_in[0];
  const int*   nidx   = (const int*)d_in[1];
  const float* conv_w = (const float*)d_in[2];
  const float* conv_b = (const float*)d_in[3];
  const float* lin_w  = (const float*)d_in[4];
  const float* lin_b  = (const float*)d_in[5];
  const float* ln_w   = (const float*)d_in[6];
  const float* ln_b   = (const float*)d_in[7];
  float* out = (float*)d_out;

  unsigned short* featsB = (unsigned short*)d_ws;                       // 51,200,000 B
  unsigned short* wfrag  = (unsigned short*)((char*)d_ws + 51200000);   //    884,736 B
  float*          biasf  = (float*)((char*)d_ws + 51200000 + 884736);   //        512 B
  int*            nidxT  = (int*)((char*)d_ws + 51200000 + 884736 + 512); // 21,600,000 B

  const size_t ws_need_tr = 51200000ULL + 884736ULL + 512ULL + 21600000ULL;
  const bool use_tr = (ws_size >= ws_need_tr);

  int n8 = N_ROWS * C_DIM / 8;  // 3,200,000
  k_cast<<<(n8 + 255) / 256, 256, 0, stream>>>(feats, featsB, n8);
  k_fold<<<(TAPS * 2048 + 128 + 255) / 256, 256, 0, stream>>>(conv_w, lin_w, conv_b, lin_b,
                                                              wfrag, biasf);
  if (use_tr) k_tr<<<N_ROWS / 64, 256, 0, stream>>>(nidx, nidxT);

  k_main<<<(N_ROWS + 63) / 64, 128, 0, stream>>>(
      featsB,
      use_tr ? (const int*)nidxT : nidx,
      use_tr ? 1 : TAPS,          // row stride (ints)
      use_tr ? N_ROWS : 1,        // tap stride (ints)
      wfrag, biasf, ln_w, ln_b, out);
}